// Round 2
// baseline (106.035 us; speedup 1.0000x reference)
//
#include <hip/hip_runtime.h>
#include <math.h>

#define NB 4096   // N events
#define BB 4      // batch
#define TI 256    // i per block
#define TJ 256    // j per slice

#if __has_builtin(__builtin_amdgcn_exp2f)
#define EXP2F __builtin_amdgcn_exp2f
#else
#define EXP2F exp2f
#endif

// Kernel 1: S[b,i] = sum_j [ (t_i - t_j > 0) & mask_j ] * exp(-beta*dt - sqdist/(2 sig^2))
// Causal tiling: blockIdx.y (j-slice) > blockIdx.x (i-tile) contributes nothing -> early exit.
__global__ __launch_bounds__(TI) void hawkes_pair(
    const float* __restrict__ loc, const float* __restrict__ times,
    const int* __restrict__ mask,
    const float* __restrict__ beta_p, const float* __restrict__ sigma_p,
    float* __restrict__ S)
{
    const int it = blockIdx.x;
    const int s  = blockIdx.y;
    if (s > it) return;                 // j-slice strictly above diagonal: all dt <= 0
    const int b   = blockIdx.z;
    const int tid = threadIdx.x;

    const float beta  = beta_p[0];
    const float sigma = sigma_p[0];
    const float L2E = 1.4426950408889634f;
    const float nb  = -beta * L2E;                    // dt coefficient (log2 domain)
    const float nc  = -L2E / (2.0f * sigma * sigma);  // sqdist coefficient

    const int i = it * TI + tid;
    const float ti = times[b * NB + i];
    const float xi = loc[(b * NB + i) * 2 + 0];
    const float yi = loc[(b * NB + i) * 2 + 1];

    // stage j tile: (t or 2.0-if-masked, x, y, pad). t=2.0 > any t_i kills via dt>0 predicate.
    __shared__ float4 jt[TJ];
    {
        const int j = s * TJ + tid;
        const float tj = times[b * NB + j];
        const bool  mj = mask[b * NB + j] != 0;   // int32 bool from harness
        float4 v;
        v.x = mj ? tj : 2.0f;
        v.y = loc[(b * NB + j) * 2 + 0];
        v.z = loc[(b * NB + j) * 2 + 1];
        v.w = 0.0f;
        jt[tid] = v;
    }
    __syncthreads();

    float acc = 0.0f;
#pragma unroll 8
    for (int jj = 0; jj < TJ; ++jj) {
        float4 v = jt[jj];                 // wave-uniform address -> LDS broadcast
        float dt = ti - v.x;
        float dx = xi - v.y;
        float dy = yi - v.z;
        float sq  = fmaf(dy, dy, dx * dx);
        float arg = fmaf(sq, nc, dt * nb); // log2-domain exponent
        float e   = EXP2F(arg);
        acc += (dt > 0.0f) ? e : 0.0f;
    }
    atomicAdd(&S[b * NB + i], acc);
}

// Kernel 2: per-batch reduction of log-intensity + compensator.
__global__ __launch_bounds__(256) void hawkes_finish(
    const float* __restrict__ loc, const float* __restrict__ times,
    const int* __restrict__ mask,
    const float* mu_p, const float* alpha_p, const float* beta_p, const float* sigma_p,
    const float* lo_p, const float* hi_p, const float* tend_p,
    const float* __restrict__ S, float* __restrict__ out)
{
    const int b   = blockIdx.x;
    const int tid = threadIdx.x;

    const float mu    = mu_p[0];
    const float alpha = alpha_p[0];
    const float beta  = beta_p[0];
    const float sigma = sigma_p[0];
    const float lo0 = lo_p[0], lo1 = lo_p[1];
    const float hi0 = hi_p[0], hi1 = hi_p[1];
    const float tend = tend_p[0];

    const float two_sig2 = 2.0f * sigma * sigma;
    const float norm = beta / ((float)M_PI * two_sig2);   // d=2 -> exponent 1
    const float an = alpha * norm;
    const float inv_ss2 = 1.0f / (sigma * sqrtf(2.0f));

    float accL = 0.0f, accC = 0.0f;
    for (int i = tid; i < NB; i += 256) {
        if (mask[b * NB + i] != 0) {
            float lam = fmaf(an, S[b * NB + i], mu);
            accL += logf(lam);
            float tmass = 1.0f - expf(-beta * (tend - times[b * NB + i]));
            float x = loc[(b * NB + i) * 2 + 0];
            float y = loc[(b * NB + i) * 2 + 1];
            float cx = 0.5f * (erff((hi0 - x) * inv_ss2) - erff((lo0 - x) * inv_ss2));
            float cy = 0.5f * (erff((hi1 - y) * inv_ss2) - erff((lo1 - y) * inv_ss2));
            accC += tmass * cx * cy;
        }
    }

    // block reduction (4 waves x 64 lanes)
    __shared__ float redL[4], redC[4];
    for (int off = 32; off > 0; off >>= 1) {
        accL += __shfl_down(accL, off, 64);
        accC += __shfl_down(accC, off, 64);
    }
    const int wave = tid >> 6, lane = tid & 63;
    if (lane == 0) { redL[wave] = accL; redC[wave] = accC; }
    __syncthreads();
    if (tid == 0) {
        float L = redL[0] + redL[1] + redL[2] + redL[3];
        float C = redC[0] + redC[1] + redC[2] + redC[3];
        float area = (hi0 - lo0) * (hi1 - lo1);
        out[b] = L - (mu * area * tend + alpha * C);
    }
}

extern "C" void kernel_launch(void* const* d_in, const int* in_sizes, int n_in,
                              void* d_out, int out_size, void* d_ws, size_t ws_size,
                              hipStream_t stream) {
    const float* loc   = (const float*)d_in[0];
    const float* times = (const float*)d_in[1];
    const int*   mask  = (const int*)d_in[2];    // bool -> int32 per harness
    const float* mu_p    = (const float*)d_in[3];
    const float* alpha_p = (const float*)d_in[4];
    const float* beta_p  = (const float*)d_in[5];
    const float* sigma_p = (const float*)d_in[6];
    const float* lo_p    = (const float*)d_in[7];
    const float* hi_p    = (const float*)d_in[8];
    const float* tend_p  = (const float*)d_in[9];
    float* out = (float*)d_out;
    float* S   = (float*)d_ws;   // B*N partial kernel sums (64 KB)

    hipMemsetAsync(S, 0, BB * NB * sizeof(float), stream);

    dim3 grid(NB / TI, NB / TJ, BB);
    hawkes_pair<<<grid, TI, 0, stream>>>(loc, times, mask, beta_p, sigma_p, S);
    hawkes_finish<<<dim3(BB), 256, 0, stream>>>(loc, times, mask, mu_p, alpha_p, beta_p,
                                                sigma_p, lo_p, hi_p, tend_p, S, out);
}

// Round 3
// 91.385 us; speedup vs baseline: 1.1603x; 1.1603x over previous
//
#include <hip/hip_runtime.h>
#include <math.h>

#define NB  4096            // N events
#define BB  4               // batch
#define TI  512             // i per block (2 per thread)
#define TJ  256             // j per slice
#define NSL (NB / TJ)       // 16 j-slices
#define NIT (NB / TI)       // 8 i-tiles
#define THR 256

#if __has_builtin(__builtin_amdgcn_exp2f)
#define EXP2F __builtin_amdgcn_exp2f
#else
#define EXP2F exp2f
#endif

// arg = nb*(t_i - t_j) + nc*((x_i-x_j)^2 + (y_i-y_j)^2)      (log2 domain)
//     = [nb*t_i + nc*(x_i^2+y_i^2)] + [-nb*t_j + nc*(x_j^2+y_j^2)]
//       + x_i*(-2nc*x_j) + y_i*(-2nc*y_j)
//     =  u_i + w_j + x_i*xp_j + y_i*yp_j
// Masked j: w_j = -3e38 -> exp2 -> 0 (and tj=2.0 kills the diagonal predicate).
// S layout: S[(b*NSL + s)*NB + i], each slot written exactly once (no memset,
// no atomics; invalid tiles write zeros).
__global__ __launch_bounds__(THR) void hawkes_pair(
    const float* __restrict__ loc, const float* __restrict__ times,
    const int* __restrict__ mask,
    const float* __restrict__ beta_p, const float* __restrict__ sigma_p,
    float* __restrict__ S)
{
    const int it  = blockIdx.x;
    const int s   = blockIdx.y;
    const int b   = blockIdx.z;
    const int tid = threadIdx.x;

    const int i0 = it * TI + tid;
    const int i1 = i0 + THR;
    float* __restrict__ Srow = S + (size_t)(b * NSL + s) * NB;

    if (s > 2 * it + 1) {               // strictly above diagonal: no causal pairs
        Srow[i0] = 0.0f;
        Srow[i1] = 0.0f;
        return;
    }

    const float beta  = beta_p[0];
    const float sigma = sigma_p[0];
    const float L2E = 1.4426950408889634f;
    const float nb  = -beta * L2E;
    const float nc  = -L2E / (2.0f * sigma * sigma);

    const float t0 = times[b * NB + i0];
    const float x0 = loc[(b * NB + i0) * 2 + 0];
    const float y0 = loc[(b * NB + i0) * 2 + 1];
    const float u0 = fmaf(nc, fmaf(x0, x0, y0 * y0), nb * t0);
    const float t1 = times[b * NB + i1];
    const float x1 = loc[(b * NB + i1) * 2 + 0];
    const float y1 = loc[(b * NB + i1) * 2 + 1];
    const float u1 = fmaf(nc, fmaf(x1, x1, y1 * y1), nb * t1);

    __shared__ float4 jt[TJ];
    {
        const int j  = s * TJ + tid;
        const float tj = times[b * NB + j];
        const float xj = loc[(b * NB + j) * 2 + 0];
        const float yj = loc[(b * NB + j) * 2 + 1];
        const bool  mj = mask[b * NB + j] != 0;
        float4 v;
        v.x = mj ? fmaf(nc, fmaf(xj, xj, yj * yj), -nb * tj) : -3.0e38f;  // w_j
        v.y = mj ? (-2.0f * nc * xj) : 0.0f;                              // xp_j
        v.z = mj ? (-2.0f * nc * yj) : 0.0f;                              // yp_j
        v.w = mj ? tj : 2.0f;                                             // for predicate
        jt[tid] = v;
    }
    __syncthreads();

    float a0 = 0.0f, a1 = 0.0f;
    if (s < 2 * it) {
        // interior: every j is strictly earlier than every i -> no predicate
#pragma unroll 8
        for (int jj = 0; jj < TJ; ++jj) {
            float4 v = jt[jj];                         // broadcast read
            float g0 = fmaf(v.y, x0, fmaf(v.z, y0, u0 + v.x));
            float g1 = fmaf(v.y, x1, fmaf(v.z, y1, u1 + v.x));
            a0 += EXP2F(g0);
            a1 += EXP2F(g1);
        }
    } else {
        // diagonal overlap: need strict dt > 0
#pragma unroll 8
        for (int jj = 0; jj < TJ; ++jj) {
            float4 v = jt[jj];
            float g0 = fmaf(v.y, x0, fmaf(v.z, y0, u0 + v.x));
            float g1 = fmaf(v.y, x1, fmaf(v.z, y1, u1 + v.x));
            float e0 = EXP2F(g0);
            float e1 = EXP2F(g1);
            a0 += (t0 > v.w) ? e0 : 0.0f;
            a1 += (t1 > v.w) ? e1 : 0.0f;
        }
    }
    Srow[i0] = a0;
    Srow[i1] = a1;
}

// Per-batch: sum slice partials, log-intensity + compensator, block-reduce.
__global__ __launch_bounds__(1024) void hawkes_finish(
    const float* __restrict__ loc, const float* __restrict__ times,
    const int* __restrict__ mask,
    const float* mu_p, const float* alpha_p, const float* beta_p, const float* sigma_p,
    const float* lo_p, const float* hi_p, const float* tend_p,
    const float* __restrict__ S, float* __restrict__ out)
{
    const int b   = blockIdx.x;
    const int tid = threadIdx.x;

    const float mu    = mu_p[0];
    const float alpha = alpha_p[0];
    const float beta  = beta_p[0];
    const float sigma = sigma_p[0];
    const float lo0 = lo_p[0], lo1 = lo_p[1];
    const float hi0 = hi_p[0], hi1 = hi_p[1];
    const float tend = tend_p[0];

    const float two_sig2 = 2.0f * sigma * sigma;
    const float an = alpha * beta / ((float)M_PI * two_sig2);   // alpha*norm, d=2
    const float inv_ss2 = 1.0f / (sigma * sqrtf(2.0f));

    float accL = 0.0f, accC = 0.0f;
    for (int i = tid; i < NB; i += 1024) {
        if (mask[b * NB + i] != 0) {
            float sum = 0.0f;
#pragma unroll
            for (int s = 0; s < NSL; ++s)
                sum += S[(size_t)(b * NSL + s) * NB + i];
            float lam = fmaf(an, sum, mu);
            accL += logf(lam);
            float tmass = 1.0f - expf(-beta * (tend - times[b * NB + i]));
            float x = loc[(b * NB + i) * 2 + 0];
            float y = loc[(b * NB + i) * 2 + 1];
            float cx = 0.5f * (erff((hi0 - x) * inv_ss2) - erff((lo0 - x) * inv_ss2));
            float cy = 0.5f * (erff((hi1 - y) * inv_ss2) - erff((lo1 - y) * inv_ss2));
            accC += tmass * cx * cy;
        }
    }

    // 16 waves x 64 lanes
    __shared__ float redL[16], redC[16];
    for (int off = 32; off > 0; off >>= 1) {
        accL += __shfl_down(accL, off, 64);
        accC += __shfl_down(accC, off, 64);
    }
    const int wave = tid >> 6, lane = tid & 63;
    if (lane == 0) { redL[wave] = accL; redC[wave] = accC; }
    __syncthreads();
    if (tid == 0) {
        float L = 0.0f, C = 0.0f;
#pragma unroll
        for (int w = 0; w < 16; ++w) { L += redL[w]; C += redC[w]; }
        float area = (hi0 - lo0) * (hi1 - lo1);
        out[b] = L - (mu * area * tend + alpha * C);
    }
}

extern "C" void kernel_launch(void* const* d_in, const int* in_sizes, int n_in,
                              void* d_out, int out_size, void* d_ws, size_t ws_size,
                              hipStream_t stream) {
    const float* loc   = (const float*)d_in[0];
    const float* times = (const float*)d_in[1];
    const int*   mask  = (const int*)d_in[2];    // bool -> int32 per harness
    const float* mu_p    = (const float*)d_in[3];
    const float* alpha_p = (const float*)d_in[4];
    const float* beta_p  = (const float*)d_in[5];
    const float* sigma_p = (const float*)d_in[6];
    const float* lo_p    = (const float*)d_in[7];
    const float* hi_p    = (const float*)d_in[8];
    const float* tend_p  = (const float*)d_in[9];
    float* out = (float*)d_out;
    float* S   = (float*)d_ws;   // [BB][NSL][NB] slice partials, 1 MB, fully overwritten

    dim3 grid(NIT, NSL, BB);
    hawkes_pair<<<grid, THR, 0, stream>>>(loc, times, mask, beta_p, sigma_p, S);
    hawkes_finish<<<dim3(BB), 1024, 0, stream>>>(loc, times, mask, mu_p, alpha_p, beta_p,
                                                 sigma_p, lo_p, hi_p, tend_p, S, out);
}